// Round 7
// baseline (129.274 us; speedup 1.0000x reference)
//
#include <hip/hip_runtime.h>

// Problem constants
#define B_   2
#define H_   16
#define L_   2048
#define D_   64
#define BLK_ 32
#define NB_  64

// LDS strides in bf16 halves
#define KSW 64   // K: 32 rows x 64, d-chunk XOR (oct ^ (row&7)), b128-aligned
#define VS  40   // V^T (pi-permuted keys): 64 rows x 40, 16B chunk XOR (C ^ (d&3))
#define OS  65   // fp32 epilogue transpose stride

typedef __bf16 bf16x8 __attribute__((ext_vector_type(8)));
typedef float  f32x4  __attribute__((ext_vector_type(4)));
typedef unsigned short u16x4 __attribute__((ext_vector_type(4)));
typedef unsigned short u16x8 __attribute__((ext_vector_type(8)));

__device__ inline unsigned short f2bf(float f) {
    unsigned int u = __builtin_bit_cast(unsigned int, f);
    unsigned int r = u + 0x7fffu + ((u >> 16) & 1u);
    return (unsigned short)(r >> 16);
}
// Barrier WITHOUT vmcnt drain (distance-2 prefetch loads stay in flight)
#define WG_BARRIER() asm volatile("s_waitcnt lgkmcnt(0)\n\ts_barrier" ::: "memory")

struct Tile {
    u16x8  kc0, kc1;   // K rows (tid>>3) and 16+(tid>>3), d-octet tid&7, bf16
    u16x4  vg[4];      // V keys wave*16 + {g*4..g*4+3} at d=lane, bf16
    float4 kpa, kpb;   // kpm[j*32 + quad*4 + r] and +16 (keys = S^T C-rows)
};

__global__ __launch_bounds__(128, 4)
void sparse_attn_kernel(const float* __restrict__ qg,
                        const float* __restrict__ kg,
                        const float* __restrict__ vg,
                        const float* __restrict__ kpm,
                        const int*   __restrict__ layout,
                        float* __restrict__ outg)
{
    __shared__ __align__(16) union {
        struct {
            unsigned short Ks[2][BLK_ * KSW];  // 8192 B
            unsigned short Vt[2][D_ * VS];     // 10240 B
        } s;
        float Os[32 * OS];                     // epilogue overlay (8320 B)
    } Lds;

    const int tid  = threadIdx.x;
    const int wave = tid >> 6;
    const int lane = tid & 63;
    const int quad = lane >> 4;
    const int l15  = lane & 15;

    // XCD swizzle: each XCD covers whole query ranges of 4 heads -> L2 locality
    const int phys = blockIdx.x;
    const int lw   = (phys & 7) * 256 + (phys >> 3);
    const int i = lw & 63;
    const int h = (lw >> 6) & 15;
    const int b = lw >> 10;

    const size_t bh = (size_t)(b * H_ + h);
    const float* kbase = kg + bh * L_ * D_;
    const float* vbase = vg + bh * L_ * D_;
    const float* kpp   = kpm + (size_t)b * L_;
    const int*   layrow = layout + (h * NB_ + i) * NB_;

    const int jbeg = i - 7;
    int act[8];
    #pragma unroll
    for (int s = 0; s < 8; ++s) {
        const int j = jbeg + s;
        act[s] = (j >= 0) ? layrow[j] : 0;
    }

    // Q fragments (B-operand of S^T = K*Q^T): lane holds Q[q=wave*16+l15][d=ks*32+quad*8+j]
    bf16x8 aq[2];
    {
        const float* qrow = qg + (bh * L_ + (size_t)i * BLK_ + wave * 16 + l15) * D_;
        #pragma unroll
        for (int ks = 0; ks < 2; ++ks) {
            float4 x = *(const float4*)&qrow[ks * 32 + quad * 8];
            float4 y = *(const float4*)&qrow[ks * 32 + quad * 8 + 4];
            u16x8 pk;
            pk[0]=f2bf(x.x); pk[1]=f2bf(x.y); pk[2]=f2bf(x.z); pk[3]=f2bf(x.w);
            pk[4]=f2bf(y.x); pk[5]=f2bf(y.y); pk[6]=f2bf(y.z); pk[7]=f2bf(y.w);
            aq[ks] = __builtin_bit_cast(bf16x8, pk);
        }
    }

    auto clampj = [&](int j) { return j < 0 ? 0 : j; };

    auto loadT = [&](int jc, Tile& T) {
        const float* kb = kbase + (size_t)jc * BLK_ * D_;
        float4 a0 = *(const float4*)&kb[tid * 8];
        float4 a1 = *(const float4*)&kb[tid * 8 + 4];
        float4 b0 = *(const float4*)&kb[(tid + 128) * 8];
        float4 b1 = *(const float4*)&kb[(tid + 128) * 8 + 4];
        u16x8 k0, k1;
        k0[0]=f2bf(a0.x); k0[1]=f2bf(a0.y); k0[2]=f2bf(a0.z); k0[3]=f2bf(a0.w);
        k0[4]=f2bf(a1.x); k0[5]=f2bf(a1.y); k0[6]=f2bf(a1.z); k0[7]=f2bf(a1.w);
        k1[0]=f2bf(b0.x); k1[1]=f2bf(b0.y); k1[2]=f2bf(b0.z); k1[3]=f2bf(b0.w);
        k1[4]=f2bf(b1.x); k1[5]=f2bf(b1.y); k1[6]=f2bf(b1.z); k1[7]=f2bf(b1.w);
        T.kc0 = k0; T.kc1 = k1;
        const float* vb = vbase + (size_t)jc * BLK_ * D_;
        #pragma unroll
        for (int g = 0; g < 4; ++g) {
            u16x4 pv;
            #pragma unroll
            for (int r = 0; r < 4; ++r)
                pv[r] = f2bf(vb[(wave * 16 + g * 4 + r) * D_ + lane]);  // coalesced
            T.vg[g] = pv;
        }
        T.kpa = *(const float4*)&kpp[jc * BLK_ + quad * 4];
        T.kpb = *(const float4*)&kpp[jc * BLK_ + 16 + quad * 4];
    };

    // pi-permuted key columns: key K<16 -> k' = (K>>2)*8 + (K&3)
    //                          key 16+Kl -> k' = (Kl>>2)*8 + 4 + (Kl&3)
    // wave0 group g (keys g*4..g*4+3)  -> chunk C=g, half-offset 0..3
    // wave1 group g (keys 16+g*4..+3)  -> chunk C=g, half-offset 4..7
    auto storeT = [&](int buf, const Tile& T) {
        const int row = tid >> 3, oct = tid & 7;
        *(u16x8*)&Lds.s.Ks[buf][row * KSW + ((oct ^ (row & 7)) * 8)]        = T.kc0;
        *(u16x8*)&Lds.s.Ks[buf][(16 + row) * KSW + ((oct ^ (row & 7)) * 8)] = T.kc1;
        const int swz = lane & 3;       // lane = d here
        const int wo  = wave * 4;
        #pragma unroll
        for (int g = 0; g < 4; ++g)
            *(u16x4*)&Lds.s.Vt[buf][lane * VS + ((g ^ swz) * 8) + wo] = T.vg[g];
    };

    // accumulators: O^T tiles (C-layout: row=d-local, col=q=l15), no-max softmax
    float lsum = 0.f;
    f32x4 Ot[4];
    #pragma unroll
    for (int t = 0; t < 4; ++t) Ot[t] = (f32x4){0.f, 0.f, 0.f, 0.f};

    auto computeT = [&](int buf, const float4& kp0, const float4& kp1) {
        // S^T = K * Q^T : A = K-frag (m=key), B = Q-frag (n=q)
        f32x4 st0 = {0.f,0.f,0.f,0.f}, st1 = {0.f,0.f,0.f,0.f};
        #pragma unroll
        for (int ks = 0; ks < 2; ++ks) {
            const int co = (((ks * 4 + quad) ^ (l15 & 7)) * 8);
            bf16x8 ka  = *(const bf16x8*)&Lds.s.Ks[buf][l15 * KSW + co];
            bf16x8 kb2 = *(const bf16x8*)&Lds.s.Ks[buf][(16 + l15) * KSW + co];
            st0 = __builtin_amdgcn_mfma_f32_16x16x32_bf16(ka,  aq[ks], st0, 0, 0, 0);
            st1 = __builtin_amdgcn_mfma_f32_16x16x32_bf16(kb2, aq[ks], st1, 0, 0, 0);
        }
        // P^T rows this lane owns: keys quad*4+r (tile0) and 16+quad*4+r (tile1)
        u16x8 bpk;
        #pragma unroll
        for (int r = 0; r < 4; ++r) {
            float p0 = __expf(st0[r] * 0.125f + kp0[r]);
            float p1 = __expf(st1[r] * 0.125f + kp1[r]);
            lsum += p0 + p1;
            bpk[r]     = f2bf(p0);   // j=r   -> key 4*quad+r      = pi(8q+j)
            bpk[4 + r] = f2bf(p1);   // j=4+r -> key 16+4*quad+r   = pi(8q+j)
        }
        bf16x8 bp = __builtin_bit_cast(bf16x8, bpk);
        // O^T += V^T * P^T (keys pi-permuted in BOTH operands; sum unchanged)
        const int swzv = l15 & 3;    // rowd & 3 == l15 & 3
        #pragma unroll
        for (int t = 0; t < 4; ++t) {
            bf16x8 av = *(const bf16x8*)&Lds.s.Vt[buf][(t * 16 + l15) * VS + ((quad ^ swzv) * 8)];
            Ot[t] = __builtin_amdgcn_mfma_f32_16x16x32_bf16(av, bp, Ot[t], 0, 0, 0);
        }
    };

    // ---- prologue ----
    Tile tiles[2];
    loadT(clampj(jbeg), tiles[0]);
    storeT(0, tiles[0]);
    float4 kpc0 = tiles[0].kpa, kpc1 = tiles[0].kpb;
    loadT(clampj(jbeg + 1), tiles[1]);
    WG_BARRIER();

    // ---- steady state: load(j+2) || compute(j) || store(j+1), one barrier/iter ----
    int cur = 0;
    #pragma unroll
    for (int s = 0; s < 8; ++s) {
        const int j = jbeg + s;
        if (s <= 5) loadT(clampj(j + 2), tiles[s & 1]);   // distance-2 prefetch
        if (act[s] != 0) computeT(cur, kpc0, kpc1);
        if (s < 7) {
            const Tile& T = tiles[(s + 1) & 1];           // loaded one iter ago
            storeT(cur ^ 1, T);
            kpc0 = T.kpa; kpc1 = T.kpb;
        }
        WG_BARRIER();
        cur ^= 1;
    }

    // ---- epilogue: reduce l across quads (cols=q), normalize, transpose O^T ----
    lsum += __shfl_xor(lsum, 16);
    lsum += __shfl_xor(lsum, 32);
    const float rinv = 1.0f / lsum;

    float* osw = &Lds.Os[(wave * 16) * OS];   // this wave's private 16 x 64 slice
    #pragma unroll
    for (int t = 0; t < 4; ++t)
        #pragma unroll
        for (int r = 0; r < 4; ++r)
            osw[l15 * OS + t * 16 + quad * 4 + r] = Ot[t][r] * rinv;
    asm volatile("s_waitcnt lgkmcnt(0)" ::: "memory");    // wave-local drain

    const int qrow = lane >> 2, sc = lane & 3;
    float* outp = outg + (bh * L_ + (size_t)i * BLK_ + wave * 16) * D_;
    #pragma unroll
    for (int c = 0; c < 4; ++c) {
        float4 gv;
        #pragma unroll
        for (int r = 0; r < 4; ++r) gv[r] = osw[qrow * OS + c * 16 + sc * 4 + r];
        *(float4*)&outp[qrow * D_ + c * 16 + sc * 4] = gv;
    }
}

extern "C" void kernel_launch(void* const* d_in, const int* in_sizes, int n_in,
                              void* d_out, int out_size, void* d_ws, size_t ws_size,
                              hipStream_t stream) {
    const float* q      = (const float*)d_in[0];
    const float* k      = (const float*)d_in[1];
    const float* v      = (const float*)d_in[2];
    const float* kpmask = (const float*)d_in[3];
    const int*   layout = (const int*)d_in[4];
    float* out = (float*)d_out;

    dim3 grid(B_ * H_ * NB_);   // 2048 WGs: one query block each, 2 waves
    dim3 block(128);
    sparse_attn_kernel<<<grid, block, 0, stream>>>(q, k, v, kpmask, layout, out);
}

// Round 8
// 106.282 us; speedup vs baseline: 1.2163x; 1.2163x over previous
//
#include <hip/hip_runtime.h>

// Problem constants
#define B_   2
#define H_   16
#define L_   2048
#define D_   64
#define BLK_ 32
#define NB_  64

// LDS strides in bf16 halves
#define KSW 64   // K: 32 rows x 64, d-chunk XOR (oct ^ (row&7)) -> conflict-free
#define VS  40   // V^T (pi-permuted keys): 64 rows x 40, chunk XOR (C ^ (d&3))
#define OS  65   // fp32 epilogue transpose stride

typedef __bf16 bf16x8 __attribute__((ext_vector_type(8)));
typedef float  f32x4  __attribute__((ext_vector_type(4)));
typedef unsigned short u16x8 __attribute__((ext_vector_type(8)));

__device__ inline unsigned short f2bf(float f) {
    unsigned int u = __builtin_bit_cast(unsigned int, f);
    unsigned int r = u + 0x7fffu + ((u >> 16) & 1u);
    return (unsigned short)(r >> 16);
}
// Barrier WITHOUT vmcnt drain (distance-2 prefetch loads stay in flight)
#define WG_BARRIER() asm volatile("s_waitcnt lgkmcnt(0)\n\ts_barrier" ::: "memory")

__global__ __launch_bounds__(128)
__attribute__((amdgpu_waves_per_eu(4, 4)))   // pin 4 waves/EU -> 128-VGPR budget, no squeeze-to-64
void sparse_attn_kernel(const float* __restrict__ qg,
                        const float* __restrict__ kg,
                        const float* __restrict__ vg,
                        const float* __restrict__ kpm,
                        const int*   __restrict__ layout,
                        float* __restrict__ outg)
{
    __shared__ __align__(16) union {
        struct {
            unsigned short Ks[2][BLK_ * KSW];  // 8192 B
            unsigned short Vt[2][D_ * VS];     // 10240 B
        } s;
        float Os[32 * OS];                     // epilogue overlay (8320 B)
    } Lds;

    const int tid  = threadIdx.x;
    const int wave = tid >> 6;
    const int lane = tid & 63;
    const int quad = lane >> 4;
    const int l15  = lane & 15;

    // XCD swizzle: each XCD covers whole query ranges of 4 heads -> L2 locality
    const int phys = blockIdx.x;
    const int lw   = (phys & 7) * 256 + (phys >> 3);
    const int i = lw & 63;
    const int h = (lw >> 6) & 15;
    const int b = lw >> 10;

    const size_t bh = (size_t)(b * H_ + h);
    const float* kbase = kg + bh * L_ * D_;
    const float* vbase = vg + bh * L_ * D_;
    const float* kpp   = kpm + (size_t)b * L_;
    const int*   layrow = layout + (h * NB_ + i) * NB_;

    const int jbeg = i - 7;
    int act[8];
    #pragma unroll
    for (int s = 0; s < 8; ++s) {
        const int j = jbeg + s;
        act[s] = (j >= 0) ? layrow[j] : 0;
    }

    // Q fragments (B-operand of S^T = K*Q^T): lane holds Q[q=wave*16+l15][d=ks*32+quad*8+j]
    bf16x8 aq[2];
    {
        const float* qrow = qg + (bh * L_ + (size_t)i * BLK_ + wave * 16 + l15) * D_;
        #pragma unroll
        for (int ks = 0; ks < 2; ++ks) {
            float4 x = *(const float4*)&qrow[ks * 32 + quad * 8];
            float4 y = *(const float4*)&qrow[ks * 32 + quad * 8 + 4];
            u16x8 pk;
            pk[0]=f2bf(x.x); pk[1]=f2bf(x.y); pk[2]=f2bf(x.z); pk[3]=f2bf(x.w);
            pk[4]=f2bf(y.x); pk[5]=f2bf(y.y); pk[6]=f2bf(y.z); pk[7]=f2bf(y.w);
            aq[ks] = __builtin_bit_cast(bf16x8, pk);
        }
    }

    auto clampj = [&](int j) { return j < 0 ? 0 : j; };

    // Carried prefetch state (slim: 32 VGPRs total for 2 slots; kpm NOT carried)
    u16x8 kc[2][2];   // K rows (tid>>3), 16+(tid>>3); d-octet tid&7
    u16x8 vc[2][2];   // two full pi-chunks per lane: wave w owns chunks 2w, 2w+1

    auto loadT = [&](int jc, int slot) {
        const float* kb = kbase + (size_t)jc * BLK_ * D_;
        float4 a0 = *(const float4*)&kb[tid * 8];
        float4 a1 = *(const float4*)&kb[tid * 8 + 4];
        float4 b0 = *(const float4*)&kb[(tid + 128) * 8];
        float4 b1 = *(const float4*)&kb[(tid + 128) * 8 + 4];
        u16x8 k0, k1;
        k0[0]=f2bf(a0.x); k0[1]=f2bf(a0.y); k0[2]=f2bf(a0.z); k0[3]=f2bf(a0.w);
        k0[4]=f2bf(a1.x); k0[5]=f2bf(a1.y); k0[6]=f2bf(a1.z); k0[7]=f2bf(a1.w);
        k1[0]=f2bf(b0.x); k1[1]=f2bf(b0.y); k1[2]=f2bf(b0.z); k1[3]=f2bf(b0.w);
        k1[4]=f2bf(b1.x); k1[5]=f2bf(b1.y); k1[6]=f2bf(b1.z); k1[7]=f2bf(b1.w);
        kc[slot][0] = k0; kc[slot][1] = k1;
        // V gather: wave w loads keys {8w..8w+7} U {16+8w..16+8w+7} at d=lane
        // -> lane owns FULL pi-chunks 2w+cc: pos r = key 4*(2w+cc)+r, pos 4+r = key 16+4*(2w+cc)+r
        const float* vb = vbase + (size_t)jc * BLK_ * D_;
        #pragma unroll
        for (int cc = 0; cc < 2; ++cc) {
            u16x8 pv;
            #pragma unroll
            for (int r = 0; r < 4; ++r) {
                pv[r]     = f2bf(vb[(wave * 8 + cc * 4 + r) * D_ + lane]);       // coalesced rows
                pv[4 + r] = f2bf(vb[(16 + wave * 8 + cc * 4 + r) * D_ + lane]);
            }
            vc[slot][cc] = pv;
        }
    };

    auto storeT = [&](int buf, int slot) {
        const int row = tid >> 3, oct = tid & 7;
        *(u16x8*)&Lds.s.Ks[buf][row * KSW + ((oct ^ (row & 7)) * 8)]        = kc[slot][0];
        *(u16x8*)&Lds.s.Ks[buf][(16 + row) * KSW + ((oct ^ (row & 7)) * 8)] = kc[slot][1];
        const int swz = lane & 3;   // lane = d here
        #pragma unroll
        for (int cc = 0; cc < 2; ++cc)   // full-chunk b128 writes: conflict-free
            *(u16x8*)&Lds.s.Vt[buf][lane * VS + (((2 * wave + cc) ^ swz) * 8)] = vc[slot][cc];
    };

    // accumulators: O^T tiles (C-layout: row=d-local, col=q=l15), no-max softmax
    float lsum = 0.f;
    f32x4 Ot[4];
    #pragma unroll
    for (int t = 0; t < 4; ++t) Ot[t] = (f32x4){0.f, 0.f, 0.f, 0.f};

    auto computeT = [&](int buf, int j) {
        // kpm loaded here (not carried): L1/L2-resident, latency hides under MFMAs
        float4 kp0 = *(const float4*)&kpp[j * BLK_ + quad * 4];
        float4 kp1 = *(const float4*)&kpp[j * BLK_ + 16 + quad * 4];
        // S^T = K * Q^T : A = K-frag (m=key), B = Q-frag (n=q)
        f32x4 st0 = {0.f,0.f,0.f,0.f}, st1 = {0.f,0.f,0.f,0.f};
        #pragma unroll
        for (int ks = 0; ks < 2; ++ks) {
            const int co = (((ks * 4 + quad) ^ (l15 & 7)) * 8);
            bf16x8 ka  = *(const bf16x8*)&Lds.s.Ks[buf][l15 * KSW + co];
            bf16x8 kb2 = *(const bf16x8*)&Lds.s.Ks[buf][(16 + l15) * KSW + co];
            st0 = __builtin_amdgcn_mfma_f32_16x16x32_bf16(ka,  aq[ks], st0, 0, 0, 0);
            st1 = __builtin_amdgcn_mfma_f32_16x16x32_bf16(kb2, aq[ks], st1, 0, 0, 0);
        }
        // P^T rows this lane owns: keys quad*4+r (tile0) and 16+quad*4+r (tile1)
        u16x8 bpk;
        #pragma unroll
        for (int r = 0; r < 4; ++r) {
            float p0 = __expf(st0[r] * 0.125f + kp0[r]);
            float p1 = __expf(st1[r] * 0.125f + kp1[r]);
            lsum += p0 + p1;
            bpk[r]     = f2bf(p0);   // j=r   -> key 4*quad+r    = pi(8q+j)
            bpk[4 + r] = f2bf(p1);   // j=4+r -> key 16+4*quad+r = pi(8q+j)
        }
        bf16x8 bp = __builtin_bit_cast(bf16x8, bpk);
        // O^T += V^T * P^T (keys pi-permuted in BOTH operands; sum unchanged)
        const int swzv = l15 & 3;
        #pragma unroll
        for (int t = 0; t < 4; ++t) {
            bf16x8 av = *(const bf16x8*)&Lds.s.Vt[buf][(t * 16 + l15) * VS + ((quad ^ swzv) * 8)];
            Ot[t] = __builtin_amdgcn_mfma_f32_16x16x32_bf16(av, bp, Ot[t], 0, 0, 0);
        }
    };

    // ---- prologue ----
    loadT(clampj(jbeg), 0);
    storeT(0, 0);
    loadT(clampj(jbeg + 1), 1);
    WG_BARRIER();

    // ---- steady state: load(j+2) || compute(j) || store(j+1), one barrier/iter ----
    int cur = 0;
    #pragma unroll
    for (int s = 0; s < 8; ++s) {
        const int j = jbeg + s;
        if (s <= 5) loadT(clampj(j + 2), s & 1);   // distance-2 prefetch
        if (act[s] != 0) computeT(cur, j);
        if (s < 7) storeT(cur ^ 1, (s + 1) & 1);   // slot loaded one iter ago
        WG_BARRIER();
        cur ^= 1;
    }

    // ---- epilogue: reduce l across quads (cols=q), normalize, transpose O^T ----
    lsum += __shfl_xor(lsum, 16);
    lsum += __shfl_xor(lsum, 32);
    const float rinv = 1.0f / lsum;

    float* osw = &Lds.Os[(wave * 16) * OS];   // this wave's private 16 x 64 slice
    #pragma unroll
    for (int t = 0; t < 4; ++t)
        #pragma unroll
        for (int r = 0; r < 4; ++r)
            osw[l15 * OS + t * 16 + quad * 4 + r] = Ot[t][r] * rinv;
    asm volatile("s_waitcnt lgkmcnt(0)" ::: "memory");    // wave-local drain

    const int qrow = lane >> 2, sc = lane & 3;
    float* outp = outg + (bh * L_ + (size_t)i * BLK_ + wave * 16) * D_;
    #pragma unroll
    for (int c = 0; c < 4; ++c) {
        float4 gv;
        #pragma unroll
        for (int r = 0; r < 4; ++r) gv[r] = osw[qrow * OS + c * 16 + sc * 4 + r];
        *(float4*)&outp[qrow * D_ + c * 16 + sc * 4] = gv;
    }
}

extern "C" void kernel_launch(void* const* d_in, const int* in_sizes, int n_in,
                              void* d_out, int out_size, void* d_ws, size_t ws_size,
                              hipStream_t stream) {
    const float* q      = (const float*)d_in[0];
    const float* k      = (const float*)d_in[1];
    const float* v      = (const float*)d_in[2];
    const float* kpmask = (const float*)d_in[3];
    const int*   layout = (const int*)d_in[4];
    float* out = (float*)d_out;

    dim3 grid(B_ * H_ * NB_);   // 2048 WGs: one query block each, 2 waves -> 8 WG/CU
    dim3 block(128);
    sparse_attn_kernel<<<grid, block, 0, stream>>>(q, k, v, kpmask, layout, out);
}